// Round 8
// baseline (259.172 us; speedup 1.0000x reference)
//
#include <hip/hip_runtime.h>
#include <hip/hip_cooperative_groups.h>

namespace cg = cooperative_groups;

#define LL 512
#define NB 128
#define TPB 256
#define BLOCKS 1024
#define NWAVES (BLOCKS * TPB / 64)          // 4096
#define RPW (NB * LL / NWAVES)              // 16 rows per wave

typedef float f32x4 __attribute__((ext_vector_type(4)));

constexpr float MAXT   = 86400.0f;
constexpr float MAXD   = 50000.0f;
constexpr float EARTH2 = 2.0f * 6367000.0f;           // 2 * EARTH
constexpr float D2R    = 0.017453292519943295f;        // pi/180
constexpr float EPSF   = 1e-12f;
constexpr float NEGV   = -1000000000.0f;

__device__ __forceinline__ float wred_sum(float v) {
    #pragma unroll
    for (int m = 32; m; m >>= 1) v += __shfl_xor(v, m, 64);
    return v;
}
__device__ __forceinline__ float wred_max(float v) {
    #pragma unroll
    for (int m = 32; m; m >>= 1) v = fmaxf(v, __shfl_xor(v, m, 64));
    return v;
}

// Pairwise (dt, ds) — pure FMA/rcp/sqrt, no libcalls.
// haversine with sin^2(d/2) = sin^2(d)/(2(1+cos d)); asin via 2-term series
// (exact to ~1e-9 below the MAXD clamp threshold).
__device__ __forceinline__ float2 pair_dtds(float t_i, float4 pi,
                                            float t_j, float4 pj) {
    float dt = fminf(fabsf(t_i - t_j), MAXT);
    float p  = pi.x * pj.x;                            // cos_lat_i * cos_lat_j
    float c1 = fmaf(pi.y, pj.y, p);                    // cos(dlat)
    float s1 = fmaf(pi.y, pj.x, -pi.x * pj.y);         // sin(dlat)
    float h1 = s1 * s1 * __builtin_amdgcn_rcpf(fmaf(2.0f, c1, 2.0f));
    float c2 = fmaf(pi.w, pj.w, pi.z * pj.z);          // cos(dlon)
    float s2 = fmaf(pi.w, pj.z, -pi.z * pj.w);         // sin(dlon)
    float h2 = s2 * s2 * __builtin_amdgcn_rcpf(fmaf(2.0f, c2, 2.0f));
    float a  = fmaf(p, h2, h1);
    float x  = __builtin_amdgcn_sqrtf(a);
    float as = x * fmaf(a, fmaf(a, 0.075f, 0.16666667f), 1.0f);
    float ds = fminf(EARTH2 * as, MAXD);
    return make_float2(dt, ds);
}

// Single cooperative kernel: phase 0 trig table -> sync -> phase A (norms +
// rowmax for valid rows; NEGV output rows for invalid rows, overlapping the
// write) -> sync -> phase B (batch max + softmax + NT stores).
// r <= 2 (unit-norm rows) so exp(rmax - r) <= e^2 needs no shift; each masked
// entry contributes exp(0) = 1 to the denominator, added analytically.
__global__ __launch_bounds__(TPB) void k_all(
    const float* __restrict__ t_s, const float* __restrict__ s_s,
    const int* __restrict__ val_len, float* __restrict__ out,
    float4* __restrict__ tab, float2* __restrict__ w_norm,
    float* __restrict__ w_rowmax)
{
    cg::grid_group grid = cg::this_grid();
    const int tid  = threadIdx.x;
    const int lane = tid & 63;
    const int gw   = blockIdx.x * (TPB / 64) + (tid >> 6);
    const int gtid = blockIdx.x * TPB + tid;

    // ---- phase 0: trig table ----
    if (gtid < NB * LL) {
        float lon = s_s[2 * gtid]     * D2R;
        float lat = s_s[2 * gtid + 1] * D2R;
        tab[gtid] = make_float4(cosf(lat), sinf(lat), cosf(lon), sinf(lon));
    }
    grid.sync();

    // ---- phase A: row norms + rowmax; NEGV rows written here ----
    #pragma unroll 1
    for (int rr = 0; rr < RPW; ++rr) {
        const int row = gw + rr * NWAVES;
        const int b = row >> 9;
        const int i = row & (LL - 1);
        if (i >= val_len[b]) {             // constant row: write it now
            if (lane == 0) w_rowmax[row] = 0.0f;   // neutral (r >= 0)
            f32x4* o4 = reinterpret_cast<f32x4*>(out + (size_t)row * LL);
            const f32x4 nv = {NEGV, NEGV, NEGV, NEGV};
            __builtin_nontemporal_store(nv, &o4[lane]);
            __builtin_nontemporal_store(nv, &o4[lane + 64]);
            continue;
        }
        const int n = i + 1;
        const float*  tb = t_s + b * LL;
        const float4* pb = tab + b * LL;
        const float  t_i = tb[i];
        const float4 pi  = pb[i];

        float dt[8], ds[8], st = 0.0f, ss = 0.0f;
        #pragma unroll
        for (int k = 0; k < 8; ++k) {
            dt[k] = 0.0f; ds[k] = 0.0f;
            if ((k << 6) < n) {            // wave-uniform chunk guard
                const int j = lane + (k << 6);
                if (j < n) {
                    float2 v = pair_dtds(t_i, pi, tb[j], pb[j]);
                    dt[k] = v.x; ds[k] = v.y;
                    st = fmaf(v.x, v.x, st);
                    ss = fmaf(v.y, v.y, ss);
                }
            }
        }
        st = wred_sum(st);
        ss = wred_sum(ss);
        const float itn = __builtin_amdgcn_rcpf(fmaxf(__builtin_amdgcn_sqrtf(st), EPSF));
        const float isn = __builtin_amdgcn_rcpf(fmaxf(__builtin_amdgcn_sqrtf(ss), EPSF));

        float mx = 0.0f;
        #pragma unroll
        for (int k = 0; k < 8; ++k) mx = fmaxf(mx, fmaf(dt[k], itn, ds[k] * isn));
        mx = wred_max(mx);
        if (lane == 0) {
            w_norm[row]   = make_float2(itn, isn);
            w_rowmax[row] = mx;
        }
    }
    grid.sync();

    // ---- phase B: batch max + softmax + store (valid rows only) ----
    #pragma unroll 1
    for (int rr = 0; rr < RPW; ++rr) {
        const int row = gw + rr * NWAVES;
        const int b = row >> 9;
        const int i = row & (LL - 1);
        if (i >= val_len[b]) continue;     // written in phase A
        const int n = i + 1;
        float* orow = out + (size_t)row * LL;

        // per-batch max of r (rowmax array is L2-resident; wave max-reduce)
        const float* rm = w_rowmax + (b << 9);
        float bm = fmaxf(rm[lane], rm[lane + 64]);
        #pragma unroll
        for (int k = 2; k < 8; ++k) bm = fmaxf(bm, rm[lane + (k << 6)]);
        const float rmx = wred_max(bm);

        const float*  tb = t_s + b * LL;
        const float4* pb = tab + b * LL;
        const float  t_i = tb[i];
        const float4 pi  = pb[i];
        const float2 nn  = w_norm[row];

        float ev[8], s = 0.0f;
        #pragma unroll
        for (int k = 0; k < 8; ++k) {
            ev[k] = 0.0f;
            if ((k << 6) < n) {            // wave-uniform chunk guard
                const int j = lane + (k << 6);
                if (j < n) {
                    float2 v = pair_dtds(t_i, pi, tb[j], pb[j]);
                    float e = __expf(rmx - fmaf(v.x, nn.x, v.y * nn.y));
                    ev[k] = e;
                    s += e;
                }
            }
        }
        s = wred_sum(s);
        const float inv = 1.0f / (s + (float)(LL - n));

        #pragma unroll
        for (int k = 0; k < 8; ++k) {
            const int j = lane + (k << 6);
            const float o = (j < n) ? ev[k] * inv : NEGV;
            __builtin_nontemporal_store(o, &orow[j]);
        }
    }
}

extern "C" void kernel_launch(void* const* d_in, const int* in_sizes, int n_in,
                              void* d_out, int out_size, void* d_ws, size_t ws_size,
                              hipStream_t stream) {
    const float* t_s     = (const float*)d_in[0];
    const float* s_s     = (const float*)d_in[1];
    const int*   val_len = (const int*)d_in[2];
    float* out = (float*)d_out;

    char* ws = (char*)d_ws;
    float4* tab      = (float4*)ws;                                  // 1 MB
    float2* w_norm   = (float2*)(ws + (size_t)NB * LL * 16);         // 512 KB
    float*  w_rowmax = (float*) (ws + (size_t)NB * LL * 24);         // 256 KB

    void* args[] = {(void*)&t_s, (void*)&s_s, (void*)&val_len, (void*)&out,
                    (void*)&tab, (void*)&w_norm, (void*)&w_rowmax};
    hipLaunchCooperativeKernel((void*)k_all, dim3(BLOCKS), dim3(TPB),
                               args, 0, stream);
}

// Round 9
// 102.043 us; speedup vs baseline: 2.5398x; 2.5398x over previous
//
#include <hip/hip_runtime.h>

#define LL 512
#define NB 128
#define TPB 1024                 // 16 waves per block
#define NWB (TPB / 64)

typedef float f32x4 __attribute__((ext_vector_type(4)));

constexpr float MAXT   = 86400.0f;
constexpr float MAXD   = 50000.0f;
constexpr float EARTH2 = 2.0f * 6367000.0f;           // 2 * EARTH
constexpr float D2R    = 0.017453292519943295f;        // pi/180
constexpr float EPSF   = 1e-12f;
constexpr float NEGV   = -1000000000.0f;

__device__ __forceinline__ float wred_sum(float v) {
    #pragma unroll
    for (int m = 32; m; m >>= 1) v += __shfl_xor(v, m, 64);
    return v;
}
__device__ __forceinline__ float wred_max(float v) {
    #pragma unroll
    for (int m = 32; m; m >>= 1) v = fmaxf(v, __shfl_xor(v, m, 64));
    return v;
}

// Pairwise (dt, ds) from SoA LDS operands — pure FMA/rcp/sqrt.
// haversine with sin^2(d/2) = sin^2(d)/(2(1+cos d)); asin via 2-term series
// (exact to ~1e-9 below the MAXD clamp threshold).
__device__ __forceinline__ float2 pair_dtds(
    float t_i, float cli, float sli, float coi, float soi,
    float t_j, float clj, float slj, float coj, float soj)
{
    float dt = fminf(fabsf(t_i - t_j), MAXT);
    float p  = cli * clj;                              // cos_lat_i * cos_lat_j
    float c1 = fmaf(sli, slj, p);                      // cos(dlat)
    float s1 = fmaf(slj, cli, -clj * sli);             // sin(dlat)
    float h1 = s1 * s1 * __builtin_amdgcn_rcpf(fmaf(2.0f, c1, 2.0f));
    float c2 = fmaf(soi, soj, coi * coj);              // cos(dlon)
    float s2 = fmaf(soj, coi, -coj * soi);             // sin(dlon)
    float h2 = s2 * s2 * __builtin_amdgcn_rcpf(fmaf(2.0f, c2, 2.0f));
    float a  = fmaf(p, h2, h1);
    float x  = __builtin_amdgcn_sqrtf(a);
    float as = x * fmaf(a, fmaf(a, 0.075f, 0.16666667f), 1.0f);
    float ds = fminf(EARTH2 * as, MAXD);
    return make_float2(dt, ds);
}

// One block = one quarter of one batch (rows i == q mod 4). Phase 1 (norms +
// batch max) is computed redundantly by all 4 blocks of the batch — cheaper
// than any cross-block sync. Invalid NEGV rows are written before phase 1 to
// overlap the write pipe with compute. r <= 2 (unit-norm rows) so
// exp(rmax - r) <= e^2 needs no shift; each masked entry contributes
// exp(0) = 1 to the denominator, added analytically.
__global__ __launch_bounds__(TPB) void k_all(
    const float* __restrict__ t_s, const float* __restrict__ s_s,
    const int* __restrict__ val_len, float* __restrict__ out)
{
    __shared__ float lts[LL];                 // time
    __shared__ float lcl[LL], lsl[LL];        // cos/sin lat
    __shared__ float lco[LL], lso[LL];        // cos/sin lon
    __shared__ float litn[LL], lisn[LL];      // row norms
    __shared__ float wmax[NWB];

    const int blk  = blockIdx.x;
    const int b    = blk >> 2;
    const int q    = blk & 3;
    const int tid  = threadIdx.x;
    const int lane = tid & 63;
    const int w    = tid >> 6;
    const int vl   = val_len[b];

    // ---- stage batch operands (SoA, conflict-free) ----
    if (tid < LL) {
        const float2 s = reinterpret_cast<const float2*>(s_s)[b * LL + tid];
        const float lon = s.x * D2R, lat = s.y * D2R;
        lts[tid] = t_s[b * LL + tid];
        lcl[tid] = __cosf(lat); lsl[tid] = __sinf(lat);
        lco[tid] = __cosf(lon); lso[tid] = __sinf(lon);
    }
    __syncthreads();

    // ---- early NEGV writes for this block's invalid rows ----
    const f32x4 nv = {NEGV, NEGV, NEGV, NEGV};
    #pragma unroll 1
    for (int mm = 0; mm < 8; ++mm) {
        const int i = q + 4 * (w + NWB * mm);
        if (i >= vl) {
            f32x4* o4 = reinterpret_cast<f32x4*>(out + ((size_t)b * LL + i) * LL);
            __builtin_nontemporal_store(nv, &o4[lane]);
            __builtin_nontemporal_store(nv, &o4[lane + 64]);
        }
    }

    // ---- phase 1: norms + rowmax for ALL valid rows (stripe i = w + 16m) ----
    float bmx = 0.0f;                          // r >= 0
    #pragma unroll 1
    for (int m = 0; m < LL / NWB; ++m) {
        const int i = w + NWB * m;
        if (i >= vl) break;                    // i increases with m
        const int n = i + 1;
        const float t_i = lts[i];
        const float cli = lcl[i], sli = lsl[i], coi = lco[i], soi = lso[i];

        float dt[8], ds[8], st = 0.0f, ss = 0.0f;
        #pragma unroll
        for (int k = 0; k < 8; ++k) {
            dt[k] = 0.0f; ds[k] = 0.0f;
            if ((k << 6) < n) {                // wave-uniform chunk guard
                const int j = lane + (k << 6);
                if (j < n) {
                    float2 v = pair_dtds(t_i, cli, sli, coi, soi,
                                         lts[j], lcl[j], lsl[j], lco[j], lso[j]);
                    dt[k] = v.x; ds[k] = v.y;
                    st = fmaf(v.x, v.x, st);
                    ss = fmaf(v.y, v.y, ss);
                }
            }
        }
        st = wred_sum(st);
        ss = wred_sum(ss);
        const float itn = __builtin_amdgcn_rcpf(fmaxf(__builtin_amdgcn_sqrtf(st), EPSF));
        const float isn = __builtin_amdgcn_rcpf(fmaxf(__builtin_amdgcn_sqrtf(ss), EPSF));
        if (lane == 0) { litn[i] = itn; lisn[i] = isn; }
        #pragma unroll
        for (int k = 0; k < 8; ++k)
            bmx = fmaxf(bmx, fmaf(dt[k], itn, ds[k] * isn));
    }
    bmx = wred_max(bmx);
    if (lane == 0) wmax[w] = bmx;
    __syncthreads();

    float rmx = wmax[0];
    #pragma unroll
    for (int k = 1; k < NWB; ++k) rmx = fmaxf(rmx, wmax[k]);

    // ---- phase 2: softmax + store for this block's valid rows ----
    #pragma unroll 1
    for (int mm = 0; mm < 8; ++mm) {
        const int i = q + 4 * (w + NWB * mm);
        if (i >= vl) continue;                 // already written
        const int n = i + 1;
        float* orow = out + ((size_t)b * LL + i) * LL;
        const float t_i = lts[i];
        const float cli = lcl[i], sli = lsl[i], coi = lco[i], soi = lso[i];
        const float itn = litn[i], isn = lisn[i];

        float ev[8], s = 0.0f;
        #pragma unroll
        for (int k = 0; k < 8; ++k) {
            ev[k] = 0.0f;
            if ((k << 6) < n) {                // wave-uniform chunk guard
                const int j = lane + (k << 6);
                if (j < n) {
                    float2 v = pair_dtds(t_i, cli, sli, coi, soi,
                                         lts[j], lcl[j], lsl[j], lco[j], lso[j]);
                    float e = __expf(rmx - fmaf(v.x, itn, v.y * isn));
                    ev[k] = e;
                    s += e;
                }
            }
        }
        s = wred_sum(s);
        const float inv = 1.0f / (s + (float)(LL - n));

        #pragma unroll
        for (int k = 0; k < 8; ++k) {
            const int j = lane + (k << 6);
            const float o = (j < n) ? ev[k] * inv : NEGV;
            __builtin_nontemporal_store(o, &orow[j]);
        }
    }
}

extern "C" void kernel_launch(void* const* d_in, const int* in_sizes, int n_in,
                              void* d_out, int out_size, void* d_ws, size_t ws_size,
                              hipStream_t stream) {
    const float* t_s     = (const float*)d_in[0];
    const float* s_s     = (const float*)d_in[1];
    const int*   val_len = (const int*)d_in[2];
    float* out = (float*)d_out;

    k_all<<<NB * 4, TPB, 0, stream>>>(t_s, s_s, val_len, out);
}

// Round 10
// 40.758 us; speedup vs baseline: 6.3588x; 2.5036x over previous
//
#include <hip/hip_runtime.h>

#define LL 512
#define NB 128

typedef float f32x4 __attribute__((ext_vector_type(4)));

constexpr float MAXT = 86400.0f;
constexpr float MAXD = 50000.0f;
constexpr float D2R  = 0.017453292519943295f;          // pi/180
constexpr float KM   = 6367000.0f * D2R;               // metres per degree
constexpr float EPSF = 1e-12f;
constexpr float NEGV = -1000000000.0f;

__device__ __forceinline__ float wred_sum(float v) {
    #pragma unroll
    for (int m = 32; m; m >>= 1) v += __shfl_xor(v, m, 64);
    return v;
}
__device__ __forceinline__ float wred_max(float v) {
    #pragma unroll
    for (int m = 32; m; m >>= 1) v = fmaxf(v, __shfl_xor(v, m, 64));
    return v;
}

// Equirectangular pair (dt, ds): small-angle haversine. All points in a
// 2-deg box and ds clamps at 50 km, so relative error vs haversine < 1%
// inside the clamp radius (threshold-safe; see round-10 notes).
__device__ __forceinline__ float2 pair_dtds(float t_i, float2 si, float clat,
                                            float t_j, float2 sj) {
    float dt   = fminf(fabsf(t_i - t_j), MAXT);
    float dlat = sj.y - si.y;
    float dlon = (sj.x - si.x) * clat;
    float d2   = fmaf(dlat, dlat, dlon * dlon);
    float ds   = fminf(KM * __builtin_amdgcn_sqrtf(d2), MAXD);
    return make_float2(dt, ds);
}

// Pass 1: one wave per row. Valid rows: inverse L2 norms + row max of r.
// Invalid rows: write the constant NEGV output row NOW (overlaps ~half the
// output write with pass1 compute). NT stores keep inputs/rowmax L2-resident.
__global__ __launch_bounds__(256) void k_pass1(
    const float* __restrict__ t_s, const float* __restrict__ s_s,
    const int* __restrict__ val_len,
    float2* __restrict__ w_norm, float* __restrict__ w_rowmax,
    float* __restrict__ out)
{
    const int tid  = threadIdx.x;
    const int lane = tid & 63;
    const int row  = blockIdx.x * 4 + (tid >> 6);
    const int b = row >> 9;
    const int i = row & (LL - 1);

    if (i >= val_len[b]) {                 // constant row: write it here
        if (lane == 0) w_rowmax[row] = 0.0f;   // neutral for batch max (r>=0)
        f32x4* o4 = reinterpret_cast<f32x4*>(out + (size_t)row * LL);
        const f32x4 nv = {NEGV, NEGV, NEGV, NEGV};
        __builtin_nontemporal_store(nv, &o4[lane]);
        __builtin_nontemporal_store(nv, &o4[lane + 64]);
        return;
    }
    const int n = i + 1;
    const float*  tb = t_s + b * LL;
    const float2* sb = reinterpret_cast<const float2*>(s_s) + b * LL;
    const float  t_i = tb[i];
    const float2 si  = sb[i];
    const float clat = __cosf(si.y * D2R);

    float dt[8], ds[8];
    float st = 0.0f, ss = 0.0f;
    #pragma unroll
    for (int k = 0; k < 8; ++k) {
        dt[k] = 0.0f; ds[k] = 0.0f;
        if ((k << 6) < n) {                // wave-uniform chunk guard
            const int j = lane + (k << 6);
            if (j < n) {
                float2 v = pair_dtds(t_i, si, clat, tb[j], sb[j]);
                dt[k] = v.x; ds[k] = v.y;
                st = fmaf(v.x, v.x, st);
                ss = fmaf(v.y, v.y, ss);
            }
        }
    }
    st = wred_sum(st);
    ss = wred_sum(ss);
    const float itn = __builtin_amdgcn_rcpf(fmaxf(__builtin_amdgcn_sqrtf(st), EPSF));
    const float isn = __builtin_amdgcn_rcpf(fmaxf(__builtin_amdgcn_sqrtf(ss), EPSF));

    float mx = 0.0f;
    #pragma unroll
    for (int k = 0; k < 8; ++k) mx = fmaxf(mx, fmaf(dt[k], itn, ds[k] * isn));
    mx = wred_max(mx);
    if (lane == 0) {
        w_norm[row]   = make_float2(itn, isn);
        w_rowmax[row] = mx;
    }
}

// Pass 2: valid rows only — per-wave batch-max reduce (L2-resident loads),
// recompute r, softmax, coalesced NT stores. r <= 2 (unit-norm rows) so
// exp(rmax - r) <= e^2 needs no shift; each masked entry contributes
// exp(0) = 1 to the denominator, added analytically.
__global__ __launch_bounds__(256) void k_pass2(
    const float* __restrict__ t_s, const float* __restrict__ s_s,
    const int* __restrict__ val_len,
    const float2* __restrict__ w_norm, const float* __restrict__ w_rowmax,
    float* __restrict__ out)
{
    const int tid  = threadIdx.x;
    const int lane = tid & 63;
    const int row  = blockIdx.x * 4 + (tid >> 6);
    const int b = row >> 9;
    const int i = row & (LL - 1);
    if (i >= val_len[b]) return;           // written by pass1
    const int n = i + 1;
    float* orow = out + (size_t)row * LL;

    // per-batch max of r (rowmax array is L2-resident; wave max-reduce)
    const float* rm = w_rowmax + (b << 9);
    float bm = fmaxf(rm[lane], rm[lane + 64]);
    #pragma unroll
    for (int k = 2; k < 8; ++k) bm = fmaxf(bm, rm[lane + (k << 6)]);
    const float rmx = wred_max(bm);

    const float*  tb = t_s + b * LL;
    const float2* sb = reinterpret_cast<const float2*>(s_s) + b * LL;
    const float  t_i = tb[i];
    const float2 si  = sb[i];
    const float clat = __cosf(si.y * D2R);
    const float2 nn  = w_norm[row];

    float ev[8];
    float s = 0.0f;
    #pragma unroll
    for (int k = 0; k < 8; ++k) {
        ev[k] = 0.0f;
        if ((k << 6) < n) {                // wave-uniform chunk guard
            const int j = lane + (k << 6);
            if (j < n) {
                float2 v = pair_dtds(t_i, si, clat, tb[j], sb[j]);
                float e = __expf(rmx - fmaf(v.x, nn.x, v.y * nn.y));
                ev[k] = e;
                s += e;
            }
        }
    }
    s = wred_sum(s);
    const float inv = 1.0f / (s + (float)(LL - n));

    #pragma unroll
    for (int k = 0; k < 8; ++k) {
        const int j = lane + (k << 6);
        const float o = (j < n) ? ev[k] * inv : NEGV;
        __builtin_nontemporal_store(o, &orow[j]);
    }
}

extern "C" void kernel_launch(void* const* d_in, const int* in_sizes, int n_in,
                              void* d_out, int out_size, void* d_ws, size_t ws_size,
                              hipStream_t stream) {
    const float* t_s     = (const float*)d_in[0];
    const float* s_s     = (const float*)d_in[1];
    const int*   val_len = (const int*)d_in[2];
    float* out = (float*)d_out;

    char* ws = (char*)d_ws;
    float2* w_norm   = (float2*)ws;                                  // 512 KB
    float*  w_rowmax = (float*)(ws + (size_t)NB * LL * 8);           // 256 KB

    k_pass1<<<NB * LL / 4, 256, 0, stream>>>(t_s, s_s, val_len, w_norm, w_rowmax, out);
    k_pass2<<<NB * LL / 4, 256, 0, stream>>>(t_s, s_s, val_len, w_norm, w_rowmax, out);
}